// Round 1
// baseline (2082.565 us; speedup 1.0000x reference)
//
#include <hip/hip_runtime.h>
#include <stdint.h>

#define T_TOK 2048
#define H_DIM 2048
#define F_DIM 7168
#define E_NUM 8
#define NPAIR (T_TOK * 2)   // 4096 token-expert pairs (K=2)
#define PAD_ROWS 128        // padding rows on h1/hid so partial-tile frag reads stay in-bounds

typedef _Float16 half8  __attribute__((ext_vector_type(8)));
typedef float    float4v __attribute__((ext_vector_type(4)));

// ---------------------------------------------------------------------------
// helpers
// ---------------------------------------------------------------------------
__device__ __forceinline__ void async_load16(const void* g, void* l) {
  // global -> LDS direct copy, 16 B per lane. LDS dest is wave-uniform base,
  // HW scatters lane i to base + i*16.
  __builtin_amdgcn_global_load_lds((__attribute__((address_space(1))) void*)(g),
                                   (__attribute__((address_space(3))) void*)(l),
                                   16, 0, 0);
}

// ---------------------------------------------------------------------------
// gating: one wave per token. logits = x @ gate_w (fp32), top-2, softmax.
// ---------------------------------------------------------------------------
__global__ __launch_bounds__(256) void gate_kernel(const float* __restrict__ x,
                                                   const float* __restrict__ gw,
                                                   int* __restrict__ tok_e,
                                                   float* __restrict__ tok_w,
                                                   int* __restrict__ counts) {
  const int l = threadIdx.x & 63;
  const int t = blockIdx.x * 4 + (threadIdx.x >> 6);
  const float* xr = x + (size_t)t * H_DIM;
  float acc[E_NUM];
#pragma unroll
  for (int e = 0; e < E_NUM; ++e) acc[e] = 0.f;
  for (int h = l; h < H_DIM; h += 64) {
    float xv = xr[h];
    float4v g0 = *(const float4v*)(gw + (size_t)h * 8);
    float4v g1 = *(const float4v*)(gw + (size_t)h * 8 + 4);
    acc[0] += xv * g0[0]; acc[1] += xv * g0[1];
    acc[2] += xv * g0[2]; acc[3] += xv * g0[3];
    acc[4] += xv * g1[0]; acc[5] += xv * g1[1];
    acc[6] += xv * g1[2]; acc[7] += xv * g1[3];
  }
#pragma unroll
  for (int e = 0; e < E_NUM; ++e) {
    float v = acc[e];
#pragma unroll
    for (int m = 32; m; m >>= 1) v += __shfl_xor(v, m, 64);
    acc[e] = v;
  }
  if (l == 0) {
    int i0 = 0; float v0 = acc[0];
#pragma unroll
    for (int e = 1; e < E_NUM; ++e) if (acc[e] > v0) { v0 = acc[e]; i0 = e; }
    int i1 = -1; float v1 = -3.0e38f;
#pragma unroll
    for (int e = 0; e < E_NUM; ++e) if (e != i0 && acc[e] > v1) { v1 = acc[e]; i1 = e; }
    float ew = __expf(v1 - v0);           // <= 1
    float w0 = 1.f / (1.f + ew);
    float w1 = ew / (1.f + ew);
    tok_e[2 * t] = i0;  tok_e[2 * t + 1] = i1;
    tok_w[2 * t] = w0;  tok_w[2 * t + 1] = w1;
    atomicAdd(&counts[i0], 1);
    atomicAdd(&counts[i1], 1);
  }
}

__global__ void scan_kernel(const int* __restrict__ counts, int* __restrict__ offsets,
                            int* __restrict__ fill) {
  if (threadIdx.x == 0 && blockIdx.x == 0) {
    int s = 0;
    for (int e = 0; e < E_NUM; ++e) { offsets[e] = s; fill[e] = s; s += counts[e]; }
  }
}

__global__ __launch_bounds__(256) void scatter_kernel(const int* __restrict__ tok_e,
                                                      const float* __restrict__ tok_w,
                                                      int* __restrict__ fill,
                                                      int* __restrict__ pair_tok,
                                                      float* __restrict__ pair_w) {
  int t = blockIdx.x * 256 + threadIdx.x;
  if (t >= T_TOK) return;
#pragma unroll
  for (int k = 0; k < 2; ++k) {
    int e = tok_e[2 * t + k];
    int slot = atomicAdd(&fill[e], 1);
    pair_tok[slot] = t;
    pair_w[slot] = tok_w[2 * t + k];
  }
}

// ---------------------------------------------------------------------------
// x fp32 -> fp16 (same layout)
// ---------------------------------------------------------------------------
__global__ __launch_bounds__(256) void cast_kernel(const float* __restrict__ x,
                                                   _Float16* __restrict__ xb) {
  size_t i = ((size_t)blockIdx.x * 256 + threadIdx.x) * 8;
  float4v a = *(const float4v*)(x + i);
  float4v b = *(const float4v*)(x + i + 4);
  half8 h;
  h[0] = (_Float16)a[0]; h[1] = (_Float16)a[1]; h[2] = (_Float16)a[2]; h[3] = (_Float16)a[3];
  h[4] = (_Float16)b[0]; h[5] = (_Float16)b[1]; h[6] = (_Float16)b[2]; h[7] = (_Float16)b[3];
  *(half8*)(xb + i) = h;
}

// ---------------------------------------------------------------------------
// weight transform: fp32 [R][C] -> fp16 [C][R] (transpose + cast), per expert.
// grid: (tiles = (R/32)*(C/128), nmat, nexperts); 256 threads.
// src/dst advance by blockIdx.z * R * C elements.
// ---------------------------------------------------------------------------
__global__ __launch_bounds__(256) void transform_kernel(const float* __restrict__ s0,
                                                        const float* __restrict__ s1,
                                                        _Float16* __restrict__ d0,
                                                        _Float16* __restrict__ d1,
                                                        int R, int C) {
  __shared__ float ls[32 * 132];
  const float* src = (blockIdx.y ? s1 : s0) + (size_t)blockIdx.z * R * C;
  _Float16* dst    = (blockIdx.y ? d1 : d0) + (size_t)blockIdx.z * R * C;
  const int ct = C >> 7;
  const int r0 = (blockIdx.x / ct) * 32;
  const int c0 = (blockIdx.x % ct) * 128;
  const int t = threadIdx.x;
  const int cc = (t & 31) * 4, rb = t >> 5;
#pragma unroll
  for (int p = 0; p < 4; ++p) {
    int r = rb + 8 * p;
    *(float4v*)&ls[r * 132 + cc] = *(const float4v*)&src[(size_t)(r0 + r) * C + c0 + cc];
  }
  __syncthreads();
  const int c = t >> 1, hf = t & 1;
  half8 v0, v1;
#pragma unroll
  for (int i = 0; i < 8; ++i) v0[i] = (_Float16)ls[(16 * hf + i) * 132 + c];
#pragma unroll
  for (int i = 0; i < 8; ++i) v1[i] = (_Float16)ls[(16 * hf + 8 + i) * 132 + c];
  size_t ob = (size_t)(c0 + c) * R + r0 + 16 * hf;
  *(half8*)&dst[ob] = v0;
  *(half8*)&dst[ob + 8] = v1;
}

// ---------------------------------------------------------------------------
// GEMM, m97 structure: 128x128 tile, BK=32, 4 waves, 16x16x32 f16 MFMA,
// 4x4 fragments per wave, global_load_lds width-16 staging.
// MODE 0: h1[slot][f]  = gather(x)[m] @ w1t          (store fp16)
// MODE 1: hid[slot][f] = silu(h1) * (gather(x) @ w3t) (store fp16)
// MODE 2: out[tok][h] += w * (hid @ w2t)  (atomic, split-K=2 via blockIdx.y)
// A is [rows][Klen] fp16 k-contiguous; B is [N][Klen] fp16 k-contiguous.
// ---------------------------------------------------------------------------
template <int MODE>
__global__ __launch_bounds__(256)
void gemm_kernel(const _Float16* __restrict__ A, const _Float16* __restrict__ B,
                 _Float16* __restrict__ C16, const _Float16* __restrict__ H1,
                 float* __restrict__ OUT,
                 const int* __restrict__ pair_tok, const float* __restrict__ pair_w,
                 const int* __restrict__ counts, const int* __restrict__ offs,
                 int ebase, long bstride, int Klen) {
  const int e = ebase + blockIdx.z;
  const int cnt = counts[e];
  int mt, kbeg, kend;
  if (MODE == 2) {  // split-K 2
    mt = blockIdx.y & 15;
    int kh = blockIdx.y >> 4;
    kbeg = kh * (Klen >> 1);
    kend = kbeg + (Klen >> 1);
  } else {
    mt = blockIdx.y; kbeg = 0; kend = Klen;
  }
  const int m0 = mt << 7;
  if (m0 >= cnt) return;
  const int off = offs[e];
  const int n0 = blockIdx.x << 7;
  const _Float16* Bb = B + (size_t)blockIdx.z * bstride;

  __shared__ _Float16 lsA[128 * 32];
  __shared__ _Float16 lsB[128 * 32];

  const int tid = threadIdx.x;
  const int l = tid & 63, w = tid >> 6;

  const _Float16 *aS0, *aS1, *bS0, *bS1;
  {
    const int i0 = 2 * w, i1 = 2 * w + 1;
    const int r0i = (i0 << 4) + (l >> 2), r1i = (i1 << 4) + (l >> 2);
    size_t ar0, ar1;
    if (MODE == 2) {
      ar0 = (size_t)(off + m0 + r0i);   // hid rows (padded buffer, always valid)
      ar1 = (size_t)(off + m0 + r1i);
    } else {
      int rr0 = m0 + r0i; if (rr0 > cnt - 1) rr0 = cnt - 1;
      int rr1 = m0 + r1i; if (rr1 > cnt - 1) rr1 = cnt - 1;
      ar0 = (size_t)pair_tok[off + rr0];
      ar1 = (size_t)pair_tok[off + rr1];
    }
    const int ch = (l & 3) << 3;
    aS0 = A + ar0 * (size_t)Klen + ch;
    aS1 = A + ar1 * (size_t)Klen + ch;
    bS0 = Bb + (size_t)(n0 + r0i) * Klen + ch;
    bS1 = Bb + (size_t)(n0 + r1i) * Klen + ch;
  }
  char* lA0 = (char*)lsA + (size_t)(2 * w) * 1024;
  char* lA1 = (char*)lsA + (size_t)(2 * w + 1) * 1024;
  char* lB0 = (char*)lsB + (size_t)(2 * w) * 1024;
  char* lB1 = (char*)lsB + (size_t)(2 * w + 1) * 1024;

  float4v acc[4][4];
#pragma unroll
  for (int i = 0; i < 4; ++i)
#pragma unroll
    for (int j = 0; j < 4; ++j) { float4v z = {0.f, 0.f, 0.f, 0.f}; acc[i][j] = z; }

  const int lm = l & 15, lq = l >> 4;
  const int wm = (w & 1) << 6, wn = (w >> 1) << 6;

  for (int k = kbeg; k < kend; k += 32) {
    __syncthreads();
    async_load16(aS0 + k, lA0);
    async_load16(aS1 + k, lA1);
    async_load16(bS0 + k, lB0);
    async_load16(bS1 + k, lB1);
    __syncthreads();   // drains vmcnt -> tile visible to all waves
    half8 a[4], b[4];
#pragma unroll
    for (int i = 0; i < 4; ++i)
      a[i] = *(const half8*)&lsA[(wm + (i << 4) + lm) * 32 + (lq << 3)];
#pragma unroll
    for (int j = 0; j < 4; ++j)
      b[j] = *(const half8*)&lsB[(wn + (j << 4) + lm) * 32 + (lq << 3)];
#pragma unroll
    for (int i = 0; i < 4; ++i)
#pragma unroll
      for (int j = 0; j < 4; ++j)
        acc[i][j] = __builtin_amdgcn_mfma_f32_16x16x32_f16(a[i], b[j], acc[i][j], 0, 0, 0);
  }

  // epilogue; C/D layout: col = lane&15, row = (lane>>4)*4 + reg
#pragma unroll
  for (int i = 0; i < 4; ++i) {
#pragma unroll
    for (int rg = 0; rg < 4; ++rg) {
      const int r = m0 + wm + (i << 4) + (lq << 2) + rg;  // local row in expert
      if (r < cnt) {
        if (MODE == 0) {
          _Float16* crow = C16 + (size_t)(off + r) * F_DIM;
#pragma unroll
          for (int j = 0; j < 4; ++j)
            crow[n0 + wn + (j << 4) + lm] = (_Float16)acc[i][j][rg];
        } else if (MODE == 1) {
          const _Float16* hrow = H1 + (size_t)(off + r) * F_DIM;
          _Float16* crow = C16 + (size_t)(off + r) * F_DIM;
#pragma unroll
          for (int j = 0; j < 4; ++j) {
            int col = n0 + wn + (j << 4) + lm;
            float h1v = (float)hrow[col];
            float s = h1v / (1.f + __expf(-h1v));   // silu
            crow[col] = (_Float16)(s * acc[i][j][rg]);
          }
        } else {
          const int slot = off + r;
          const float wt = pair_w[slot];
          float* orow = OUT + (size_t)pair_tok[slot] * H_DIM;
#pragma unroll
          for (int j = 0; j < 4; ++j)
            atomicAdd(&orow[n0 + wn + (j << 4) + lm], wt * acc[i][j][rg]);
        }
      }
    }
  }
}

// ---------------------------------------------------------------------------
// host
// ---------------------------------------------------------------------------
extern "C" void kernel_launch(void* const* d_in, const int* in_sizes, int n_in,
                              void* d_out, int out_size, void* d_ws, size_t ws_size,
                              hipStream_t stream) {
  const float* x  = (const float*)d_in[0];
  const float* gw = (const float*)d_in[1];
  const float* w1 = (const float*)d_in[2];
  const float* w3 = (const float*)d_in[3];
  const float* w2 = (const float*)d_in[4];
  float* out = (float*)d_out;

  char* ws = (char*)d_ws;
  size_t p = 0;
  auto alloc = [&](size_t bytes) -> void* {
    void* r = ws + p;
    p = (p + bytes + 255) & ~(size_t)255;
    return r;
  };
  int*   counts   = (int*)alloc(E_NUM * 4);
  int*   offsets  = (int*)alloc(E_NUM * 4);
  int*   fill     = (int*)alloc(E_NUM * 4);
  int*   tok_e    = (int*)alloc((size_t)T_TOK * 2 * 4);
  float* tok_w    = (float*)alloc((size_t)T_TOK * 2 * 4);
  int*   pair_tok = (int*)alloc((size_t)NPAIR * 4);
  float* pair_w   = (float*)alloc((size_t)NPAIR * 4);
  _Float16* xb    = (_Float16*)alloc((size_t)T_TOK * H_DIM * 2);
  _Float16* h1b   = (_Float16*)alloc((size_t)(NPAIR + PAD_ROWS) * F_DIM * 2);
  _Float16* hidb  = (_Float16*)alloc((size_t)(NPAIR + PAD_ROWS) * F_DIM * 2);

  const size_t wmat = (size_t)F_DIM * H_DIM;      // elements per expert matrix
  const size_t wbytes = wmat * 2;
  const bool big = (ws_size >= p + 2 * E_NUM * wbytes);

  hipMemsetAsync(out, 0, (size_t)T_TOK * H_DIM * 4, stream);
  hipMemsetAsync(counts, 0, E_NUM * 4, stream);
  cast_kernel<<<2048, 256, 0, stream>>>(x, xb);
  gate_kernel<<<T_TOK / 4, 256, 0, stream>>>(x, gw, tok_e, tok_w, counts);
  scan_kernel<<<1, 64, 0, stream>>>(counts, offsets, fill);
  scatter_kernel<<<T_TOK / 256, 256, 0, stream>>>(tok_e, tok_w, fill, pair_tok, pair_w);

  if (big) {
    _Float16* w1t = (_Float16*)alloc(E_NUM * wbytes);
    _Float16* w3t = (_Float16*)alloc(E_NUM * wbytes);
    _Float16* w2t = w1t;  // reuse after G1 is done (stream-ordered)
    transform_kernel<<<dim3(3584, 2, 8), 256, 0, stream>>>(w1, w3, w1t, w3t, H_DIM, F_DIM);
    gemm_kernel<0><<<dim3(56, 16, 8), 256, 0, stream>>>(xb, w1t, h1b, nullptr, nullptr,
        pair_tok, pair_w, counts, offsets, 0, (long)wmat, H_DIM);
    gemm_kernel<1><<<dim3(56, 16, 8), 256, 0, stream>>>(xb, w3t, hidb, h1b, nullptr,
        pair_tok, pair_w, counts, offsets, 0, (long)wmat, H_DIM);
    transform_kernel<<<dim3(3584, 1, 8), 256, 0, stream>>>(w2, nullptr, w2t, nullptr, F_DIM, H_DIM);
    gemm_kernel<2><<<dim3(16, 32, 8), 256, 0, stream>>>(hidb, w2t, nullptr, nullptr, out,
        pair_tok, pair_w, counts, offsets, 0, (long)wmat, F_DIM);
  } else {
    _Float16* w1t = (_Float16*)alloc(wbytes);
    _Float16* w3t = (_Float16*)alloc(wbytes);
    _Float16* w2t = (_Float16*)alloc(wbytes);
    for (int e = 0; e < E_NUM; ++e) {
      transform_kernel<<<dim3(3584, 2, 1), 256, 0, stream>>>(
          w1 + (size_t)e * wmat, w3 + (size_t)e * wmat, w1t, w3t, H_DIM, F_DIM);
      gemm_kernel<0><<<dim3(56, 16, 1), 256, 0, stream>>>(xb, w1t, h1b, nullptr, nullptr,
          pair_tok, pair_w, counts, offsets, e, 0L, H_DIM);
      gemm_kernel<1><<<dim3(56, 16, 1), 256, 0, stream>>>(xb, w3t, hidb, h1b, nullptr,
          pair_tok, pair_w, counts, offsets, e, 0L, H_DIM);
      transform_kernel<<<dim3(3584, 1, 1), 256, 0, stream>>>(
          w2 + (size_t)e * wmat, nullptr, w2t, nullptr, F_DIM, H_DIM);
      gemm_kernel<2><<<dim3(16, 32, 1), 256, 0, stream>>>(hidb, w2t, nullptr, nullptr, out,
          pair_tok, pair_w, counts, offsets, e, 0L, F_DIM);
    }
  }
}